// Round 4
// baseline (762.182 us; speedup 1.0000x reference)
//
#include <hip/hip_runtime.h>
#include <math.h>

#define BB 4
#define TT 2048
#define EE 1024
#define HH 16
#define DD 64
#define MM (BB*TT)   // 8192 tokens

typedef unsigned short u16;
typedef __bf16 bf16x8 __attribute__((ext_vector_type(8)));
typedef float  f32x4  __attribute__((ext_vector_type(4)));

__device__ inline float bf2f(u16 u){ union{unsigned int i; float f;} v; v.i=((unsigned int)u)<<16; return v.f; }
__device__ inline u16 f2bf(float f){ union{float f; unsigned int i;} v; v.f=f; return (u16)((v.i + 0x7fffu + ((v.i>>16)&1u))>>16); }
__device__ inline u16 f2bf_trunc(float f){ union{float f; unsigned int i;} v; v.f=f; return (u16)(v.i>>16); }

__device__ inline void gload_lds16(const void* g, void* l){
  __builtin_amdgcn_global_load_lds((__attribute__((address_space(1))) void*)g,
                                   (__attribute__((address_space(3))) void*)l, 16, 0, 0);
}

// ---------------- tiled transpose f32 -> bf16: W[K][N] -> WT[N][K] ----------------
__global__ __launch_bounds__(256) void transpose_tile(
    const float* __restrict__ W, u16* __restrict__ WT, int N, int K)
{
    __shared__ float t[32][33];
    const int n0 = blockIdx.x*32, k0 = blockIdx.y*32;
    const int tx = threadIdx.x, ty = threadIdx.y;   // 32 x 8
    #pragma unroll
    for (int j=0;j<4;j++)
        t[ty + j*8][tx] = W[(size_t)(k0 + ty + j*8)*N + n0 + tx];
    __syncthreads();
    #pragma unroll
    for (int j=0;j<4;j++)
        WT[(size_t)(n0 + ty + j*8)*K + k0 + tx] = f2bf(t[tx][ty + j*8]);
}

// ---------------- bf16 transpose V[bh][t][d] -> VT[bh][d][t] ----------------
__global__ __launch_bounds__(256) void transpose_v(
    const u16* __restrict__ V, u16* __restrict__ VT)
{
    __shared__ u16 t[32][34];
    const int bh = blockIdx.z;
    const int t0 = blockIdx.x*32;
    const int d0 = blockIdx.y*32;
    const int tx = threadIdx.x, ty = threadIdx.y;   // 32 x 8
    const u16* Vb = V + (size_t)bh*TT*DD;
    u16* VTb = VT + (size_t)bh*TT*DD;
    #pragma unroll
    for (int j=0;j<4;j++)
        t[ty+j*8][tx] = Vb[(size_t)(t0+ty+j*8)*DD + d0+tx];
    __syncthreads();
    #pragma unroll
    for (int j=0;j<4;j++)
        VTb[(size_t)(d0+ty+j*8)*TT + t0+tx] = t[tx][ty+j*8];
}

// ---------------- QKV repack f32 -> bf16 ----------------
__global__ __launch_bounds__(256) void repack_qkv_tiled(
    const float* __restrict__ wq, const float* __restrict__ wk, const float* __restrict__ wv,
    u16* __restrict__ WT)
{
    __shared__ float t[32][33];
    const int z = blockIdx.z, which = z>>4, hh = z&15;
    const int d0 = blockIdx.x*32, c0 = blockIdx.y*32;
    const int tx = threadIdx.x, ty = threadIdx.y;
    const float* w = which==0 ? wq : (which==1 ? wk : wv);
    #pragma unroll
    for (int j=0;j<4;j++)
        t[ty + j*8][tx] = w[((size_t)hh*EE + c0 + ty + j*8)*DD + d0 + tx];
    __syncthreads();
    #pragma unroll
    for (int j=0;j<4;j++)
        WT[(size_t)(which*1024 + hh*64 + d0 + ty + j*8)*1024 + c0 + tx] = f2bf(t[tx][ty + j*8]);
}

__global__ __launch_bounds__(256) void copy_bias_qkv(
    const float* __restrict__ bq, const float* __restrict__ bk, const float* __restrict__ bv,
    float* __restrict__ bias)
{
    int i = blockIdx.x*256 + threadIdx.x;   // < 3072
    const float* b = i<1024 ? bq : (i<2048 ? bk : bv);
    bias[i] = b[i & 1023];
}

// ---------------- embed + LN1 ----------------
__global__ __launch_bounds__(256) void embed_ln1(
    const int* __restrict__ ids, const float* __restrict__ wte, const float* __restrict__ wpe,
    const float* __restrict__ g, const float* __restrict__ b,
    float* __restrict__ x_out, u16* __restrict__ h_out)
{
    const int token = blockIdx.x;
    const int t = token & (TT-1);
    const int id = ids[token];
    const int tid = threadIdx.x;
    float vals[4]; float s=0.f, s2=0.f;
    #pragma unroll
    for (int i=0;i<4;i++){
        int e = tid + i*256;
        float v = wte[(size_t)id*EE + e] + wpe[(size_t)t*EE + e];
        vals[i]=v; s+=v; s2+=v*v;
    }
    for (int off=32; off>=1; off>>=1){ s += __shfl_xor(s,off); s2 += __shfl_xor(s2,off); }
    __shared__ float red[8];
    int wave=tid>>6, lane=tid&63;
    if (lane==0){ red[wave]=s; red[4+wave]=s2; }
    __syncthreads();
    s = red[0]+red[1]+red[2]+red[3];
    s2 = red[4]+red[5]+red[6]+red[7];
    float mu = s*(1.f/EE);
    float var = s2*(1.f/EE) - mu*mu;
    float rstd = rsqrtf(var + 1e-5f);
    #pragma unroll
    for (int i=0;i<4;i++){
        int e = tid + i*256; float v = vals[i];
        x_out[(size_t)token*EE + e] = v;
        h_out[(size_t)token*EE + e] = f2bf((v-mu)*rstd*g[e] + b[e]);
    }
}

// ---------------- LN2 ----------------
__global__ __launch_bounds__(256) void ln_fwd(
    const float* __restrict__ xin, const float* __restrict__ g, const float* __restrict__ b,
    u16* __restrict__ hout)
{
    const int token = blockIdx.x;
    const int tid = threadIdx.x;
    float vals[4]; float s=0.f, s2=0.f;
    #pragma unroll
    for (int i=0;i<4;i++){
        int e = tid + i*256;
        float v = xin[(size_t)token*EE + e];
        vals[i]=v; s+=v; s2+=v*v;
    }
    for (int off=32; off>=1; off>>=1){ s += __shfl_xor(s,off); s2 += __shfl_xor(s2,off); }
    __shared__ float red[8];
    int wave=tid>>6, lane=tid&63;
    if (lane==0){ red[wave]=s; red[4+wave]=s2; }
    __syncthreads();
    s = red[0]+red[1]+red[2]+red[3];
    s2 = red[4]+red[5]+red[6]+red[7];
    float mu = s*(1.f/EE);
    float var = s2*(1.f/EE) - mu*mu;
    float rstd = rsqrtf(var + 1e-5f);
    #pragma unroll
    for (int i=0;i<4;i++){
        int e = tid + i*256; float v = vals[i];
        hout[(size_t)token*EE + e] = f2bf((v-mu)*rstd*g[e] + b[e]);
    }
}

// ======================= shared GEMM helpers =======================
#define VMCNTW(N) asm volatile("s_waitcnt vmcnt(" #N ")" ::: "memory")
#define LGKMW(N)  asm volatile("s_waitcnt lgkmcnt(" #N ")" ::: "memory")
#define SCHEDB()  __builtin_amdgcn_sched_barrier(0)
#define BAR()     { SCHEDB(); __builtin_amdgcn_s_barrier(); SCHEDB(); }

__device__ __forceinline__ bf16x8 fld(const u16* base, int row, int j){
    return *(const bf16x8*)&base[(row<<6) + ((j ^ (row&7))<<3)];
}

// ============ GEMM 128x256, BK=64, 8 waves (2x4, 64x64/wave), 2-phase ==========
// Counted-vmcnt pipelined; all four model GEMMs use this. Grids are exact
// multiples of 256 CUs (out/proj: 256, QKV: 768, FC: 1024).
// LDS 96 KiB: As[2][128*64], Bs[2][256*64]. Stage unit = 64 rows x 64 cols (8 KB,
// 1 gload_lds16/thread). Per K-tile: P0 {read A(8)+Blo(4); bar; lgkm0; 16 MFMA; bar}
// P1 {read Bhi(4); stage kt+2 A0,A1,B0,B1; bar; lgkm0; 16 MFMA; bar}
// tail {stage kt+2 B2,B3; vmcnt(6); bar}.  Steady-state 6 loads in flight.
template<int MODE>
__global__ __launch_bounds__(512,2) void gemm128(
    const u16* __restrict__ A, const u16* __restrict__ BT, const float* __restrict__ bias,
    float* CoutF, const float* resid, u16* __restrict__ CoutH,
    u16* __restrict__ q_out, u16* __restrict__ k_out, u16* __restrict__ v_out,
    int Ndim, int Kdim)
{
    __shared__ alignas(16) u16 As[2][128*64];
    __shared__ alignas(16) u16 Bs[2][256*64];
    const int tid = threadIdx.x, wave = tid>>6, lane = tid&63;
    const int quad = (lane>>4)&3, l16 = lane&15;
    const int wr = wave>>2, wc = wave&3;           // 2 x 4 wave grid

    // XCD-aware bijective block swizzle (grid is a multiple of 8)
    const int nwg = gridDim.x;
    const int chunk = nwg>>3;
    int id = blockIdx.x;
    id = (id&7)*chunk + (id>>3);
    const int nT = Ndim>>8;
    const int n0 = (id % nT) << 8;
    const int m0 = (id / nT) << 7;                 // M = 8192 -> 64 row tiles

    const int rS = tid>>3;                         // 0..63
    const int jS = (tid&7) ^ (rS&7);
    const size_t off0 = (size_t)rS*Kdim + (size_t)(jS<<3);
    const u16* pA = A  + (size_t)m0*Kdim;
    const u16* pB = BT + (size_t)n0*Kdim;

#define STG(ARR, GP, BUF, U, KT)                                               \
    gload_lds16((GP) + (size_t)((U)*64)*Kdim + (size_t)(KT)*64 + off0,         \
                &ARR[BUF][(U)*4096 + wave*512]);

    // prologue: tile0 (6 units), tile1 (6 units)
    STG(As,pA,0,0,0); STG(As,pA,0,1,0);
    STG(Bs,pB,0,0,0); STG(Bs,pB,0,1,0); STG(Bs,pB,0,2,0); STG(Bs,pB,0,3,0);
    STG(As,pA,1,0,1); STG(As,pA,1,1,1);
    STG(Bs,pB,1,0,1); STG(Bs,pB,1,1,1); STG(Bs,pB,1,2,1); STG(Bs,pB,1,3,1);

    f32x4 acc[4][4];
    const f32x4 zf = {0.f,0.f,0.f,0.f};
    #pragma unroll
    for (int i=0;i<4;i++)
        #pragma unroll
        for (int j=0;j<4;j++) acc[i][j]=zf;

    bf16x8 af[4][2], bfr[2][2];

#define LDA8()                                                                 \
  { _Pragma("unroll") for (int mt=0; mt<4; mt++)                               \
    { _Pragma("unroll") for (int kh=0; kh<2; kh++)                             \
        af[mt][kh] = fld(Ab, (wr<<6) + (mt<<4) + l16, kh*4+quad); } }
#define LDB4(NTB)                                                              \
  { _Pragma("unroll") for (int nt=0; nt<2; nt++)                               \
    { _Pragma("unroll") for (int kh=0; kh<2; kh++)                             \
        bfr[nt][kh] = fld(Bb, (wc<<6) + (((NTB)+nt)<<4) + l16, kh*4+quad); } }
#define MFMA16B(NT0)                                                           \
  __builtin_amdgcn_s_setprio(1);                                               \
  { _Pragma("unroll") for (int mt=0; mt<4; mt++)                               \
    { _Pragma("unroll") for (int nt=0; nt<2; nt++)                             \
      { _Pragma("unroll") for (int kh=0; kh<2; kh++)                           \
          acc[mt][(NT0)+nt] = __builtin_amdgcn_mfma_f32_16x16x32_bf16(         \
              af[mt][kh], bfr[nt][kh], acc[mt][(NT0)+nt], 0,0,0);              \
      } } }                                                                    \
  __builtin_amdgcn_s_setprio(0);

    VMCNTW(6);
    BAR();

    const int NT = Kdim>>6;
    for (int kt=0; kt<NT; ++kt){
        const int b = kt&1;
        const u16* Ab = As[b];
        const u16* Bb = Bs[b];
        // ---- P0: read A (8) + B-low (4) ----
        LDA8(); LDB4(0);
        LGKMW(8);
        BAR(); LGKMW(0); SCHEDB();
        MFMA16B(0);
        BAR();
        // ---- P1: read B-high (4); stage kt+2 A0,A1,B0,B1 (regions free) ----
        LDB4(2);
        if (kt+2 < NT){
            STG(As,pA,b,0,kt+2); STG(As,pA,b,1,kt+2);
            STG(Bs,pB,b,0,kt+2); STG(Bs,pB,b,1,kt+2);
        }
        BAR(); LGKMW(0); SCHEDB();
        MFMA16B(2);
        BAR();
        // ---- tail: stage kt+2 B2,B3 (B-high readers done before last barrier) --
        if (kt+2 < NT){
            STG(Bs,pB,b,2,kt+2); STG(Bs,pB,b,3,kt+2);
            VMCNTW(6);
        } else if (kt+1 < NT) { VMCNTW(0); }
        BAR();
    }
#undef STG
#undef LDA8
#undef LDB4
#undef MFMA16B

    // ---------------- epilogue ----------------
    #pragma unroll
    for (int mt=0; mt<4; mt++){
        const int mrow = m0 + (wr<<6) + (mt<<4) + (quad<<2);
        #pragma unroll
        for (int nt=0; nt<4; nt++){
            const int n = n0 + (wc<<6) + (nt<<4) + l16;
            #pragma unroll
            for (int r=0;r<4;r++){
                const int m = mrow + r;
                float v = acc[mt][nt][r] + bias[n];
                if (MODE==0){
                    int which = n>>10, hd = n&1023, hh = hd>>6, d = hd&63;
                    u16* dst = which==0 ? q_out : (which==1 ? k_out : v_out);
                    int bb = m>>11, t = m&(TT-1);
                    dst[(((size_t)(bb*HH+hh)*TT + t)<<6) + d] = f2bf(v);
                } else if (MODE==1){
                    size_t idx = (size_t)m*Ndim + n;
                    CoutF[idx] = resid[idx] + v;
                } else {
                    size_t idx = (size_t)m*Ndim + n;
                    CoutH[idx] = f2bf(0.5f*v*(1.0f + erff(v*0.70710678118f)));
                }
            }
        }
    }
}

// ---------------- flash attention v4: causal-paired, double-buffered K/V ---------
// Counted-vmcnt staging: tile kt+1's 4 loads issued at loop top, vmcnt(4) keeps
// them in flight while computing tile kt (never drains mid-loop).
__device__ __forceinline__ void attn_proc_tile(
    int kt, int q0, int quad, int l16,
    const u16* Ks, const u16* Vs, u16* Psw,
    const bf16x8 (&qf)[2][2], f32x4 (&oacc)[2][4], float (&lsum)[2][4])
{
    if (kt > ((q0+31)>>6)) return;           // wave-uniform
    const f32x4 zf = {0.f,0.f,0.f,0.f};
    f32x4 a[2][4];
    #pragma unroll
    for (int m=0;m<2;m++)
        #pragma unroll
        for (int st=0;st<4;st++) a[m][st]=zf;
    __builtin_amdgcn_s_setprio(1);
    #pragma unroll
    for (int h2=0;h2<2;h2++){
        #pragma unroll
        for (int st=0;st<4;st++){
            const int s = st*16 + l16;
            const int jc = h2*4 + quad;
            bf16x8 kf = *(const bf16x8*)&Ks[s*64 + (jc ^ (s&7))*8];
            #pragma unroll
            for (int m=0;m<2;m++)
                a[m][st] = __builtin_amdgcn_mfma_f32_16x16x32_bf16(qf[m][h2], kf, a[m][st], 0,0,0);
        }
    }
    __builtin_amdgcn_s_setprio(0);
    const bool needMask = (kt*64 + 63 > q0);
    #pragma unroll
    for (int m=0;m<2;m++){
        const int q0m = q0 + m*16;
        #pragma unroll
        for (int st=0;st<4;st++){
            #pragma unroll
            for (int r=0;r<4;r++){
                float p = exp2f(fminf(a[m][st][r]*0.1803369f, 40.f));
                if (needMask){
                    const int qrow = q0m + quad*4 + r;
                    const int s = kt*64 + st*16 + l16;
                    if (s > qrow) p = 0.f;
                }
                lsum[m][r] += p;
                const int ql = m*16 + quad*4 + r;
                const int sc3 = st*2 + (l16>>3);
                Psw[ql*64 + (sc3 ^ (ql&7))*8 + (l16&7)] = f2bf_trunc(p);
            }
        }
    }
    __builtin_amdgcn_s_setprio(1);
    #pragma unroll
    for (int kh=0; kh<2; kh++){
        const int jc = kh*4 + quad;
        bf16x8 pf[2];
        #pragma unroll
        for (int m=0;m<2;m++){
            const int ql16 = m*16 + l16;
            pf[m] = *(const bf16x8*)&Psw[ql16*64 + (jc ^ (ql16&7))*8];
        }
        #pragma unroll
        for (int dt=0; dt<4; dt++){
            const int d = dt*16 + l16;
            bf16x8 vf = *(const bf16x8*)&Vs[d*64 + (jc ^ (d&7))*8];
            #pragma unroll
            for (int m=0;m<2;m++)
                oacc[m][dt] = __builtin_amdgcn_mfma_f32_16x16x32_bf16(pf[m], vf, oacc[m][dt], 0,0,0);
        }
    }
    __builtin_amdgcn_s_setprio(0);
}

__global__ __launch_bounds__(256,2) void attn_kernel(
    const u16* __restrict__ Q, const u16* __restrict__ K, const u16* __restrict__ VT,
    u16* __restrict__ O)
{
    __shared__ u16 Ks[2][64*64];
    __shared__ u16 Vs[2][64*64];
    __shared__ u16 Ps[4*2048];
    const int tid = threadIdx.x, wave = tid>>6, lane = tid&63;
    const int quad = lane>>4, l16 = lane&15;
    const int id = blockIdx.x;
    const int bh   = (id&7) | ((id>>6)<<3);
    const int pair = (id>>3)&7;
    const int qtA = pair, qtB = 15-pair;
    const size_t base = (size_t)bh*TT*DD;
    const u16* Qb = Q + base;
    const u16* Kb = K + base;
    const u16* VTb = VT + base;
    const int qA0 = qtA*128 + wave*32;
    const int qB0 = qtB*128 + wave*32;
    u16* Psw = &Ps[wave*2048];

    bf16x8 qfA[2][2], qfB[2][2];
    #pragma unroll
    for (int m=0;m<2;m++)
        #pragma unroll
        for (int h2=0;h2<2;h2++){
            qfA[m][h2] = *(const bf16x8*)&Qb[(size_t)(qA0+m*16+l16)*DD + h2*32 + quad*8];
            qfB[m][h2] = *(const bf16x8*)&Qb[(size_t)(qB0+m*16+l16)*DD + h2*32 + quad*8];
        }
    // drain Q-fragment loads so vmcnt below counts staging loads only
    VMCNTW(0); SCHEDB();

    const f32x4 zf = {0.f,0.f,0.f,0.f};
    f32x4 oaccA[2][4], oaccB[2][4];
    float lsumA[2][4], lsumB[2][4];
    #pragma unroll
    for (int m=0;m<2;m++){
        #pragma unroll
        for (int dt=0;dt<4;dt++){ oaccA[m][dt]=zf; oaccB[m][dt]=zf; }
        #pragma unroll
        for (int r=0;r<4;r++){ lsumA[m][r]=0.f; lsumB[m][r]=0.f; }
    }

    const int ktMax = 31 - 2*pair;     // tile B's diagonal (>= tile A's range)

    const int c0 = wave*64 + lane, c1 = 256 + wave*64 + lane;
    const int r0 = c0>>3, j0 = (c0&7) ^ (r0&7);
    const int r1 = c1>>3, j1 = (c1&7) ^ (r1&7);

#define STAGEKV(KT, BUF)                                                       \
  { const int s0 = (KT)*64;                                                    \
    gload_lds16(Kb  + (size_t)(s0+r0)*DD + j0*8, &Ks[BUF][wave*512]);          \
    gload_lds16(Kb  + (size_t)(s0+r1)*DD + j1*8, &Ks[BUF][(4+wave)*512]);      \
    gload_lds16(VTb + (size_t)r0*TT + s0 + j0*8, &Vs[BUF][wave*512]);          \
    gload_lds16(VTb + (size_t)r1*TT + s0 + j1*8, &Vs[BUF][(4+wave)*512]); }

    STAGEKV(0, 0);
    for (int kt=0; kt<=ktMax; kt++){
        const int b = kt&1;
        // prefetch next tile into the other buffer (freed by previous trailing BAR)
        if (kt < ktMax){ STAGEKV(kt+1, b^1); VMCNTW(4); }
        else           { VMCNTW(0); }
        BAR();
        attn_proc_tile(kt, qB0, quad, l16, Ks[b], Vs[b], Psw, qfB, oaccB, lsumB);
        attn_proc_tile(kt, qA0, quad, l16, Ks[b], Vs[b], Psw, qfA, oaccA, lsumA);
        BAR();
    }
#undef STAGEKV

    #pragma unroll
    for (int off=1; off<16; off<<=1)
        #pragma unroll
        for (int m=0;m<2;m++)
            #pragma unroll
            for (int r=0;r<4;r++){
                lsumA[m][r] += __shfl_xor(lsumA[m][r], off);
                lsumB[m][r] += __shfl_xor(lsumB[m][r], off);
            }

    const int bb = bh>>4, hh = bh&15;
    #pragma unroll
    for (int m=0;m<2;m++)
        #pragma unroll
        for (int dt=0;dt<4;dt++)
            #pragma unroll
            for (int r=0;r<4;r++){
                int t = qA0 + m*16 + quad*4 + r;
                O[(size_t)(bb*TT + t)*EE + hh*64 + dt*16 + l16] = f2bf(oaccA[m][dt][r] / lsumA[m][r]);
                t = qB0 + m*16 + quad*4 + r;
                O[(size_t)(bb*TT + t)*EE + hh*64 + dt*16 + l16] = f2bf(oaccB[m][dt][r] / lsumB[m][r]);
            }
}

extern "C" void kernel_launch(void* const* d_in, const int* in_sizes, int n_in,
                              void* d_out, int out_size, void* d_ws, size_t ws_size,
                              hipStream_t stream)
{
    (void)in_sizes; (void)n_in; (void)out_size; (void)ws_size;
    const int*   ids  = (const int*)d_in[0];
    const float* wte  = (const float*)d_in[1];
    const float* wpe  = (const float*)d_in[2];
    const float* wq   = (const float*)d_in[3];
    const float* wk   = (const float*)d_in[4];
    const float* wv   = (const float*)d_in[5];
    const float* bq   = (const float*)d_in[6];
    const float* bk   = (const float*)d_in[7];
    const float* bv   = (const float*)d_in[8];
    const float* wproj= (const float*)d_in[9];
    const float* bproj= (const float*)d_in[10];
    const float* ln1g = (const float*)d_in[11];
    const float* ln1b = (const float*)d_in[12];
    const float* ln2g = (const float*)d_in[13];
    const float* ln2b = (const float*)d_in[14];
    const float* wfc  = (const float*)d_in[15];
    const float* bfc  = (const float*)d_in[16];
    const float* wout = (const float*)d_in[17];
    const float* bout = (const float*)d_in[18];

    const size_t MTOK = (size_t)MM*EE;       // 8M elems
    char* p = (char*)d_ws;
    float* x    = (float*)p;  p += MTOK*sizeof(float);
    u16*  h     = (u16*)p;    p += MTOK*sizeof(u16);
    u16*  Qb    = (u16*)p;    p += MTOK*sizeof(u16);
    u16*  Kb    = (u16*)p;    p += MTOK*sizeof(u16);
    u16*  Vb    = (u16*)p;    p += MTOK*sizeof(u16);
    u16*  Ob    = (u16*)p;    p += MTOK*sizeof(u16);
    u16*  fcact = Qb;                        // overlay: Q/K/V/O dead by MLP
    u16*  VTv   = h;                         // overlay: h dead between QKV gemm and LN2
    u16*  WqkvT = (u16*)p;    p += (size_t)3072*1024*sizeof(u16);
    float* biasq= (float*)p;  p += 3072*sizeof(float);
    u16*  wprojT= (u16*)p;    p += (size_t)1024*1024*sizeof(u16);
    u16*  wfcT  = (u16*)p;    p += (size_t)4096*1024*sizeof(u16);
    u16*  woutT = (u16*)p;    p += (size_t)1024*4096*sizeof(u16);
    float* out  = (float*)d_out;

    repack_qkv_tiled<<<dim3(2,32,48),dim3(32,8),0,stream>>>(wq,wk,wv,WqkvT);
    copy_bias_qkv<<<12,256,0,stream>>>(bq,bk,bv,biasq);
    transpose_tile<<<dim3(32,32), dim3(32,8),0,stream>>>(wproj, wprojT, 1024, 1024);
    transpose_tile<<<dim3(128,32),dim3(32,8),0,stream>>>(wfc,   wfcT,   4096, 1024);
    transpose_tile<<<dim3(32,128),dim3(32,8),0,stream>>>(wout,  woutT,  1024, 4096);
    embed_ln1<<<MM,256,0,stream>>>(ids, wte, wpe, ln1g, ln1b, x, h);
    // QKV: 128x256 tiles -> grid 64*12 = 768 = 3 exact rounds of 256 CUs
    gemm128<0><<<768,512,0,stream>>>(h, WqkvT, biasq, nullptr,nullptr,nullptr, Qb,Kb,Vb, 3072, 1024);
    transpose_v<<<dim3(64,2,64),dim3(32,8),0,stream>>>(Vb, VTv);
    attn_kernel<<<512,256,0,stream>>>(Qb,Kb,VTv,Ob);
    // proj: 128x256 -> grid 256 = full GPU
    gemm128<1><<<256,512,0,stream>>>(Ob, wprojT, bproj, x, x, nullptr, nullptr,nullptr,nullptr, 1024, 1024);
    ln_fwd<<<MM,256,0,stream>>>(x, ln2g, ln2b, h);
    // FC: 128x256 -> grid 64*16 = 1024 = 4 exact rounds
    gemm128<2><<<1024,512,0,stream>>>(h, wfcT, bfc, nullptr,nullptr, fcact, nullptr,nullptr,nullptr, 4096, 1024);
    // out: 128x256 -> grid 256 = full GPU
    gemm128<1><<<256,512,0,stream>>>(fcact, woutT, bout, out, x, nullptr, nullptr,nullptr,nullptr, 1024, 4096);
}

// Round 5
// 740.503 us; speedup vs baseline: 1.0293x; 1.0293x over previous
//
#include <hip/hip_runtime.h>
#include <math.h>

#define BB 4
#define TT 2048
#define EE 1024
#define HH 16
#define DD 64
#define MM (BB*TT)   // 8192 tokens

typedef unsigned short u16;
typedef __bf16 bf16x8 __attribute__((ext_vector_type(8)));
typedef float  f32x4  __attribute__((ext_vector_type(4)));

__device__ inline float bf2f(u16 u){ union{unsigned int i; float f;} v; v.i=((unsigned int)u)<<16; return v.f; }
__device__ inline u16 f2bf(float f){ union{float f; unsigned int i;} v; v.f=f; return (u16)((v.i + 0x7fffu + ((v.i>>16)&1u))>>16); }
__device__ inline u16 f2bf_trunc(float f){ union{float f; unsigned int i;} v; v.f=f; return (u16)(v.i>>16); }

__device__ inline void gload_lds16(const void* g, void* l){
  __builtin_amdgcn_global_load_lds((__attribute__((address_space(1))) void*)g,
                                   (__attribute__((address_space(3))) void*)l, 16, 0, 0);
}

// ---------------- tiled transpose f32 -> bf16: W[K][N] -> WT[N][K] ----------------
__global__ __launch_bounds__(256) void transpose_tile(
    const float* __restrict__ W, u16* __restrict__ WT, int N, int K)
{
    __shared__ float t[32][33];
    const int n0 = blockIdx.x*32, k0 = blockIdx.y*32;
    const int tx = threadIdx.x, ty = threadIdx.y;   // 32 x 8
    #pragma unroll
    for (int j=0;j<4;j++)
        t[ty + j*8][tx] = W[(size_t)(k0 + ty + j*8)*N + n0 + tx];
    __syncthreads();
    #pragma unroll
    for (int j=0;j<4;j++)
        WT[(size_t)(n0 + ty + j*8)*K + k0 + tx] = f2bf(t[tx][ty + j*8]);
}

// ---------------- bf16 transpose V[bh][t][d] -> VT[bh][d][t] ----------------
__global__ __launch_bounds__(256) void transpose_v(
    const u16* __restrict__ V, u16* __restrict__ VT)
{
    __shared__ u16 t[32][34];
    const int bh = blockIdx.z;
    const int t0 = blockIdx.x*32;
    const int d0 = blockIdx.y*32;
    const int tx = threadIdx.x, ty = threadIdx.y;   // 32 x 8
    const u16* Vb = V + (size_t)bh*TT*DD;
    u16* VTb = VT + (size_t)bh*TT*DD;
    #pragma unroll
    for (int j=0;j<4;j++)
        t[ty+j*8][tx] = Vb[(size_t)(t0+ty+j*8)*DD + d0+tx];
    __syncthreads();
    #pragma unroll
    for (int j=0;j<4;j++)
        VTb[(size_t)(d0+ty+j*8)*TT + t0+tx] = t[tx][ty+j*8];
}

// ---------------- QKV repack f32 -> bf16 ----------------
__global__ __launch_bounds__(256) void repack_qkv_tiled(
    const float* __restrict__ wq, const float* __restrict__ wk, const float* __restrict__ wv,
    u16* __restrict__ WT)
{
    __shared__ float t[32][33];
    const int z = blockIdx.z, which = z>>4, hh = z&15;
    const int d0 = blockIdx.x*32, c0 = blockIdx.y*32;
    const int tx = threadIdx.x, ty = threadIdx.y;
    const float* w = which==0 ? wq : (which==1 ? wk : wv);
    #pragma unroll
    for (int j=0;j<4;j++)
        t[ty + j*8][tx] = w[((size_t)hh*EE + c0 + ty + j*8)*DD + d0 + tx];
    __syncthreads();
    #pragma unroll
    for (int j=0;j<4;j++)
        WT[(size_t)(which*1024 + hh*64 + d0 + ty + j*8)*1024 + c0 + tx] = f2bf(t[tx][ty + j*8]);
}

__global__ __launch_bounds__(256) void copy_bias_qkv(
    const float* __restrict__ bq, const float* __restrict__ bk, const float* __restrict__ bv,
    float* __restrict__ bias)
{
    int i = blockIdx.x*256 + threadIdx.x;   // < 3072
    const float* b = i<1024 ? bq : (i<2048 ? bk : bv);
    bias[i] = b[i & 1023];
}

// ---------------- embed + LN1 ----------------
__global__ __launch_bounds__(256) void embed_ln1(
    const int* __restrict__ ids, const float* __restrict__ wte, const float* __restrict__ wpe,
    const float* __restrict__ g, const float* __restrict__ b,
    float* __restrict__ x_out, u16* __restrict__ h_out)
{
    const int token = blockIdx.x;
    const int t = token & (TT-1);
    const int id = ids[token];
    const int tid = threadIdx.x;
    float vals[4]; float s=0.f, s2=0.f;
    #pragma unroll
    for (int i=0;i<4;i++){
        int e = tid + i*256;
        float v = wte[(size_t)id*EE + e] + wpe[(size_t)t*EE + e];
        vals[i]=v; s+=v; s2+=v*v;
    }
    for (int off=32; off>=1; off>>=1){ s += __shfl_xor(s,off); s2 += __shfl_xor(s2,off); }
    __shared__ float red[8];
    int wave=tid>>6, lane=tid&63;
    if (lane==0){ red[wave]=s; red[4+wave]=s2; }
    __syncthreads();
    s = red[0]+red[1]+red[2]+red[3];
    s2 = red[4]+red[5]+red[6]+red[7];
    float mu = s*(1.f/EE);
    float var = s2*(1.f/EE) - mu*mu;
    float rstd = rsqrtf(var + 1e-5f);
    #pragma unroll
    for (int i=0;i<4;i++){
        int e = tid + i*256; float v = vals[i];
        x_out[(size_t)token*EE + e] = v;
        h_out[(size_t)token*EE + e] = f2bf((v-mu)*rstd*g[e] + b[e]);
    }
}

// ---------------- LN2 ----------------
__global__ __launch_bounds__(256) void ln_fwd(
    const float* __restrict__ xin, const float* __restrict__ g, const float* __restrict__ b,
    u16* __restrict__ hout)
{
    const int token = blockIdx.x;
    const int tid = threadIdx.x;
    float vals[4]; float s=0.f, s2=0.f;
    #pragma unroll
    for (int i=0;i<4;i++){
        int e = tid + i*256;
        float v = xin[(size_t)token*EE + e];
        vals[i]=v; s+=v; s2+=v*v;
    }
    for (int off=32; off>=1; off>>=1){ s += __shfl_xor(s,off); s2 += __shfl_xor(s2,off); }
    __shared__ float red[8];
    int wave=tid>>6, lane=tid&63;
    if (lane==0){ red[wave]=s; red[4+wave]=s2; }
    __syncthreads();
    s = red[0]+red[1]+red[2]+red[3];
    s2 = red[4]+red[5]+red[6]+red[7];
    float mu = s*(1.f/EE);
    float var = s2*(1.f/EE) - mu*mu;
    float rstd = rsqrtf(var + 1e-5f);
    #pragma unroll
    for (int i=0;i<4;i++){
        int e = tid + i*256; float v = vals[i];
        hout[(size_t)token*EE + e] = f2bf((v-mu)*rstd*g[e] + b[e]);
    }
}

// ======================= shared GEMM helpers =======================
#define VMCNTW(N) asm volatile("s_waitcnt vmcnt(" #N ")" ::: "memory")
#define LGKMW(N)  asm volatile("s_waitcnt lgkmcnt(" #N ")" ::: "memory")
#define SCHEDB()  __builtin_amdgcn_sched_barrier(0)
#define BAR()     { SCHEDB(); __builtin_amdgcn_s_barrier(); SCHEDB(); }

__device__ __forceinline__ bf16x8 fld(const u16* base, int row, int j){
    return *(const bf16x8*)&base[(row<<6) + ((j ^ (row&7))<<3)];
}

// ---- common epilogue element writer ----
template<int MODE>
__device__ __forceinline__ void epi_write(
    int m, int n, float v, int Ndim,
    float* CoutF, const float* resid, u16* CoutH,
    u16* q_out, u16* k_out, u16* v_out)
{
    if (MODE==0){
        int which = n>>10, hd = n&1023, hh = hd>>6, d = hd&63;
        u16* dst = which==0 ? q_out : (which==1 ? k_out : v_out);
        int bb = m>>11, t = m&(TT-1);
        dst[(((size_t)(bb*HH+hh)*TT + t)<<6) + d] = f2bf(v);
    } else if (MODE==1){
        size_t idx = (size_t)m*Ndim + n;
        CoutF[idx] = resid[idx] + v;
    } else {
        size_t idx = (size_t)m*Ndim + n;
        CoutH[idx] = f2bf(0.5f*v*(1.0f + erff(v*0.70710678118f)));
    }
}

// ============ GEMM 256x256, BK=64, 8 waves, 4-phase counted-vmcnt ============
template<int MODE>
__device__ __forceinline__ void gemm256_body(
    const u16* __restrict__ A, const u16* __restrict__ BT, const float* __restrict__ bias,
    float* CoutF, const float* resid, u16* __restrict__ CoutH,
    u16* __restrict__ q_out, u16* __restrict__ k_out, u16* __restrict__ v_out,
    int Ndim, int Kdim)
{
    __shared__ alignas(16) u16 As[2][256*64];
    __shared__ alignas(16) u16 Bs[2][256*64];
    const int tid = threadIdx.x, wave = tid>>6, lane = tid&63;
    const int quad = (lane>>4)&3, l16 = lane&15;
    const int wr = wave>>2, wc = wave&3;           // 2 x 4 wave grid

    // XCD-aware bijective block swizzle (grid always a multiple of 8)
    const int nwg = gridDim.x;
    const int chunk = nwg>>3;
    int id = blockIdx.x;
    id = (id&7)*chunk + (id>>3);
    const int m0 = (id & 31) << 8;                 // M = 8192 -> 32 row tiles
    const int n0 = (id >> 5) << 8;

    const int rS = tid>>3;
    const int jS = (tid&7) ^ (rS&7);
    const size_t off0   = (size_t)rS*Kdim + (size_t)(jS<<3);
    const size_t ofs64K = (size_t)64*Kdim;
    const u16* pA = A  + (size_t)m0*Kdim;
    const u16* pB = BT + (size_t)n0*Kdim;

#define STAGE(ARR, GP, BUF, H, KT)                                             \
  { const u16* _g = (GP) + (size_t)((H)*128)*Kdim + (size_t)(KT)*64 + off0;    \
    gload_lds16(_g,          &ARR[BUF][(H)*8192 + wave*512]);                  \
    gload_lds16(_g + ofs64K, &ARR[BUF][(H)*8192 + 4096 + wave*512]); }

    // prologue: tile0's 4 halves are the 8 oldest loads, then 3 halves of tile1
    STAGE(As, pA, 0, 0, 0);
    STAGE(Bs, pB, 0, 0, 0);
    STAGE(Bs, pB, 0, 1, 0);
    STAGE(As, pA, 0, 1, 0);
    STAGE(As, pA, 1, 0, 1);
    STAGE(Bs, pB, 1, 0, 1);
    STAGE(Bs, pB, 1, 1, 1);

    f32x4 acc[8][4];
    const f32x4 zf = {0.f,0.f,0.f,0.f};
    #pragma unroll
    for (int i=0;i<8;i++)
        #pragma unroll
        for (int j=0;j<4;j++) acc[i][j]=zf;

    bf16x8 af[4][2], bfr[4][2];

#define LDA(HROW)                                                              \
  { _Pragma("unroll") for (int mt=0; mt<4; mt++)                               \
    { _Pragma("unroll") for (int kh=0; kh<2; kh++)                             \
        af[mt][kh] = fld(Ab, (HROW) + (wr<<6) + (mt<<4) + l16, kh*4+quad); } }
#define LDB(HROW, NTB)                                                         \
  { _Pragma("unroll") for (int nt=0; nt<2; nt++)                               \
    { _Pragma("unroll") for (int kh=0; kh<2; kh++)                             \
        bfr[(NTB)+nt][kh] = fld(Bb, (HROW) + (wc<<5) + (nt<<4) + l16, kh*4+quad); } }
#define MFMA16(MT0, NT0)                                                       \
  __builtin_amdgcn_s_setprio(1);                                               \
  { _Pragma("unroll") for (int mt=0; mt<4; mt++)                               \
    { _Pragma("unroll") for (int nt=0; nt<2; nt++)                             \
      { _Pragma("unroll") for (int kh=0; kh<2; kh++)                           \
          acc[(MT0)+mt][(NT0)+nt] = __builtin_amdgcn_mfma_f32_16x16x32_bf16(   \
              af[mt][kh], bfr[(NT0)+nt][kh], acc[(MT0)+mt][(NT0)+nt], 0,0,0);  \
      } } }                                                                    \
  __builtin_amdgcn_s_setprio(0);

    // wait tile0 landed (all waves), publish
    VMCNTW(6);
    BAR();

    const int NT = Kdim>>6;
    for (int kt=0; kt<NT; ++kt){
        const int b = kt&1;
        const u16* Ab = As[b];
        const u16* Bb = Bs[b];
        // ---- P0: A-low + B-low reads (12); stage A1(kt+1) -> buf[b^1] ----
        LDA(0); LDB(0,0);
        if (kt+1 < NT) STAGE(As, pA, b^1, 1, kt+1);
        LGKMW(8);
        BAR(); LGKMW(0); SCHEDB();
        MFMA16(0,0);
        BAR();
        // ---- P1: B-high reads (4); stage A0(kt+2) (A-low region free) ----
        LDB(128,2);
        if (kt+2 < NT) STAGE(As, pA, b, 0, kt+2);
        BAR(); LGKMW(0); SCHEDB();
        MFMA16(0,2);
        BAR();
        // ---- P2: A-high reads (8); stage B0(kt+2) (B-low region free) ----
        LDA(128);
        if (kt+2 < NT) STAGE(Bs, pB, b, 0, kt+2);
        BAR(); LGKMW(0); SCHEDB();
        MFMA16(4,2);
        BAR();
        // ---- P3: no reads; stage B1(kt+2) (B-high region free) ----
        if (kt+2 < NT) STAGE(Bs, pB, b, 1, kt+2);
        BAR();
        MFMA16(4,0);
        // tile boundary: next tile's 4 halves complete after this wait+barrier
        if (kt+2 < NT)      { VMCNTW(6); }
        else if (kt+1 < NT) { VMCNTW(0); }
        BAR();
    }
#undef STAGE
#undef LDA
#undef LDB
#undef MFMA16

    // ---------------- epilogue ----------------
    #pragma unroll
    for (int mt=0; mt<8; mt++){
        const int mrow = m0 + ((mt<4) ? (wr<<6)+(mt<<4) : 128+(wr<<6)+((mt-4)<<4)) + (quad<<2);
        #pragma unroll
        for (int nt=0; nt<4; nt++){
            const int n = n0 + ((nt<2) ? (wc<<5)+(nt<<4) : 128+(wc<<5)+((nt-2)<<4)) + l16;
            #pragma unroll
            for (int r=0;r<4;r++)
                epi_write<MODE>(mrow + r, n, acc[mt][nt][r] + bias[n], Ndim,
                                CoutF, resid, CoutH, q_out, k_out, v_out);
        }
    }
}

// ============ GEMM 128x256, BK=64, 8 waves (2x4, 64x64/wave), 2-phase ==========
template<int MODE>
__device__ __forceinline__ void gemm128_body(
    const u16* __restrict__ A, const u16* __restrict__ BT, const float* __restrict__ bias,
    float* CoutF, const float* resid, u16* __restrict__ CoutH,
    u16* __restrict__ q_out, u16* __restrict__ k_out, u16* __restrict__ v_out,
    int Ndim, int Kdim)
{
    __shared__ alignas(16) u16 As[2][128*64];
    __shared__ alignas(16) u16 Bs[2][256*64];
    const int tid = threadIdx.x, wave = tid>>6, lane = tid&63;
    const int quad = (lane>>4)&3, l16 = lane&15;
    const int wr = wave>>2, wc = wave&3;           // 2 x 4 wave grid

    // XCD-aware bijective block swizzle (grid is a multiple of 8)
    const int nwg = gridDim.x;
    const int chunk = nwg>>3;
    int id = blockIdx.x;
    id = (id&7)*chunk + (id>>3);
    const int nT = Ndim>>8;
    const int n0 = (id % nT) << 8;
    const int m0 = (id / nT) << 7;                 // M = 8192 -> 64 row tiles

    const int rS = tid>>3;                         // 0..63
    const int jS = (tid&7) ^ (rS&7);
    const size_t off0 = (size_t)rS*Kdim + (size_t)(jS<<3);
    const u16* pA = A  + (size_t)m0*Kdim;
    const u16* pB = BT + (size_t)n0*Kdim;

#define STG(ARR, GP, BUF, U, KT)                                               \
    gload_lds16((GP) + (size_t)((U)*64)*Kdim + (size_t)(KT)*64 + off0,         \
                &ARR[BUF][(U)*4096 + wave*512]);

    // prologue: tile0 (6 units), tile1 (6 units)
    STG(As,pA,0,0,0); STG(As,pA,0,1,0);
    STG(Bs,pB,0,0,0); STG(Bs,pB,0,1,0); STG(Bs,pB,0,2,0); STG(Bs,pB,0,3,0);
    STG(As,pA,1,0,1); STG(As,pA,1,1,1);
    STG(Bs,pB,1,0,1); STG(Bs,pB,1,1,1); STG(Bs,pB,1,2,1); STG(Bs,pB,1,3,1);

    f32x4 acc[4][4];
    const f32x4 zf = {0.f,0.f,0.f,0.f};
    #pragma unroll
    for (int i=0;i<4;i++)
        #pragma unroll
        for (int j=0;j<4;j++) acc[i][j]=zf;

    bf16x8 af[4][2], bfr[2][2];

#define LDA8()                                                                 \
  { _Pragma("unroll") for (int mt=0; mt<4; mt++)                               \
    { _Pragma("unroll") for (int kh=0; kh<2; kh++)                             \
        af[mt][kh] = fld(Ab, (wr<<6) + (mt<<4) + l16, kh*4+quad); } }
#define LDB4(NTB)                                                              \
  { _Pragma("unroll") for (int nt=0; nt<2; nt++)                               \
    { _Pragma("unroll") for (int kh=0; kh<2; kh++)                             \
        bfr[nt][kh] = fld(Bb, (wc<<6) + (((NTB)+nt)<<4) + l16, kh*4+quad); } }
#define MFMA16B(NT0)                                                           \
  __builtin_amdgcn_s_setprio(1);                                               \
  { _Pragma("unroll") for (int mt=0; mt<4; mt++)                               \
    { _Pragma("unroll") for (int nt=0; nt<2; nt++)                             \
      { _Pragma("unroll") for (int kh=0; kh<2; kh++)                           \
          acc[mt][(NT0)+nt] = __builtin_amdgcn_mfma_f32_16x16x32_bf16(         \
              af[mt][kh], bfr[nt][kh], acc[mt][(NT0)+nt], 0,0,0);              \
      } } }                                                                    \
  __builtin_amdgcn_s_setprio(0);

    VMCNTW(6);
    BAR();

    const int NT = Kdim>>6;
    for (int kt=0; kt<NT; ++kt){
        const int b = kt&1;
        const u16* Ab = As[b];
        const u16* Bb = Bs[b];
        // ---- P0: read A (8) + B-low (4) ----
        LDA8(); LDB4(0);
        LGKMW(8);
        BAR(); LGKMW(0); SCHEDB();
        MFMA16B(0);
        BAR();
        // ---- P1: read B-high (4); stage kt+2 A0,A1,B0,B1 (regions free) ----
        LDB4(2);
        if (kt+2 < NT){
            STG(As,pA,b,0,kt+2); STG(As,pA,b,1,kt+2);
            STG(Bs,pB,b,0,kt+2); STG(Bs,pB,b,1,kt+2);
        }
        BAR(); LGKMW(0); SCHEDB();
        MFMA16B(2);
        BAR();
        // ---- tail: stage kt+2 B2,B3 (B-high readers done before last barrier) --
        if (kt+2 < NT){
            STG(Bs,pB,b,2,kt+2); STG(Bs,pB,b,3,kt+2);
            VMCNTW(6);
        } else if (kt+1 < NT) { VMCNTW(0); }
        BAR();
    }
#undef STG
#undef LDA8
#undef LDB4
#undef MFMA16B

    // ---------------- epilogue ----------------
    #pragma unroll
    for (int mt=0; mt<4; mt++){
        const int mrow = m0 + (wr<<6) + (mt<<4) + (quad<<2);
        #pragma unroll
        for (int nt=0; nt<4; nt++){
            const int n = n0 + (wc<<6) + (nt<<4) + l16;
            #pragma unroll
            for (int r=0;r<4;r++)
                epi_write<MODE>(mrow + r, n, acc[mt][nt][r] + bias[n], Ndim,
                                CoutF, resid, CoutH, q_out, k_out, v_out);
        }
    }
}

// ---- distinctly-named wrappers so rocprof decomposes per-GEMM time ----
__global__ __launch_bounds__(512,2) void gemm_qkv(
    const u16* __restrict__ A, const u16* __restrict__ BT, const float* __restrict__ bias,
    u16* __restrict__ q_out, u16* __restrict__ k_out, u16* __restrict__ v_out)
{
    gemm128_body<0>(A, BT, bias, nullptr, nullptr, nullptr, q_out, k_out, v_out, 3072, 1024);
}
__global__ __launch_bounds__(512,2) void gemm_proj(
    const u16* __restrict__ A, const u16* __restrict__ BT, const float* __restrict__ bias,
    float* CoutF, const float* resid)
{
    gemm128_body<1>(A, BT, bias, CoutF, resid, nullptr, nullptr, nullptr, nullptr, 1024, 1024);
}
__global__ __launch_bounds__(512,2) void gemm_out(
    const u16* __restrict__ A, const u16* __restrict__ BT, const float* __restrict__ bias,
    float* CoutF, const float* resid)
{
    gemm128_body<1>(A, BT, bias, CoutF, resid, nullptr, nullptr, nullptr, nullptr, 1024, 4096);
}
__global__ __launch_bounds__(512,2) void gemm_fc(
    const u16* __restrict__ A, const u16* __restrict__ BT, const float* __restrict__ bias,
    u16* __restrict__ CoutH)
{
    gemm256_body<2>(A, BT, bias, nullptr, nullptr, CoutH, nullptr, nullptr, nullptr, 4096, 1024);
}

// ---------------- flash attention v4: causal-paired, double-buffered K/V ---------
__device__ __forceinline__ void attn_proc_tile(
    int kt, int q0, int quad, int l16,
    const u16* Ks, const u16* Vs, u16* Psw,
    const bf16x8 (&qf)[2][2], f32x4 (&oacc)[2][4], float (&lsum)[2][4])
{
    if (kt > ((q0+31)>>6)) return;           // wave-uniform
    const f32x4 zf = {0.f,0.f,0.f,0.f};
    f32x4 a[2][4];
    #pragma unroll
    for (int m=0;m<2;m++)
        #pragma unroll
        for (int st=0;st<4;st++) a[m][st]=zf;
    __builtin_amdgcn_s_setprio(1);
    #pragma unroll
    for (int h2=0;h2<2;h2++){
        #pragma unroll
        for (int st=0;st<4;st++){
            const int s = st*16 + l16;
            const int jc = h2*4 + quad;
            bf16x8 kf = *(const bf16x8*)&Ks[s*64 + (jc ^ (s&7))*8];
            #pragma unroll
            for (int m=0;m<2;m++)
                a[m][st] = __builtin_amdgcn_mfma_f32_16x16x32_bf16(qf[m][h2], kf, a[m][st], 0,0,0);
        }
    }
    __builtin_amdgcn_s_setprio(0);
    const bool needMask = (kt*64 + 63 > q0);
    #pragma unroll
    for (int m=0;m<2;m++){
        const int q0m = q0 + m*16;
        #pragma unroll
        for (int st=0;st<4;st++){
            #pragma unroll
            for (int r=0;r<4;r++){
                float p = exp2f(fminf(a[m][st][r]*0.1803369f, 40.f));
                if (needMask){
                    const int qrow = q0m + quad*4 + r;
                    const int s = kt*64 + st*16 + l16;
                    if (s > qrow) p = 0.f;
                }
                lsum[m][r] += p;
                const int ql = m*16 + quad*4 + r;
                const int sc3 = st*2 + (l16>>3);
                Psw[ql*64 + (sc3 ^ (ql&7))*8 + (l16&7)] = f2bf_trunc(p);
            }
        }
    }
    __builtin_amdgcn_s_setprio(1);
    #pragma unroll
    for (int kh=0; kh<2; kh++){
        const int jc = kh*4 + quad;
        bf16x8 pf[2];
        #pragma unroll
        for (int m=0;m<2;m++){
            const int ql16 = m*16 + l16;
            pf[m] = *(const bf16x8*)&Psw[ql16*64 + (jc ^ (ql16&7))*8];
        }
        #pragma unroll
        for (int dt=0; dt<4; dt++){
            const int d = dt*16 + l16;
            bf16x8 vf = *(const bf16x8*)&Vs[d*64 + (jc ^ (d&7))*8];
            #pragma unroll
            for (int m=0;m<2;m++)
                oacc[m][dt] = __builtin_amdgcn_mfma_f32_16x16x32_bf16(pf[m], vf, oacc[m][dt], 0,0,0);
        }
    }
    __builtin_amdgcn_s_setprio(0);
}

__global__ __launch_bounds__(256,2) void attn_kernel(
    const u16* __restrict__ Q, const u16* __restrict__ K, const u16* __restrict__ VT,
    u16* __restrict__ O)
{
    __shared__ u16 Ks[2][64*64];
    __shared__ u16 Vs[2][64*64];
    __shared__ u16 Ps[4*2048];
    const int tid = threadIdx.x, wave = tid>>6, lane = tid&63;
    const int quad = lane>>4, l16 = lane&15;
    const int id = blockIdx.x;
    const int bh   = (id&7) | ((id>>6)<<3);
    const int pair = (id>>3)&7;
    const int qtA = pair, qtB = 15-pair;
    const size_t base = (size_t)bh*TT*DD;
    const u16* Qb = Q + base;
    const u16* Kb = K + base;
    const u16* VTb = VT + base;
    const int qA0 = qtA*128 + wave*32;
    const int qB0 = qtB*128 + wave*32;
    u16* Psw = &Ps[wave*2048];

    bf16x8 qfA[2][2], qfB[2][2];
    #pragma unroll
    for (int m=0;m<2;m++)
        #pragma unroll
        for (int h2=0;h2<2;h2++){
            qfA[m][h2] = *(const bf16x8*)&Qb[(size_t)(qA0+m*16+l16)*DD + h2*32 + quad*8];
            qfB[m][h2] = *(const bf16x8*)&Qb[(size_t)(qB0+m*16+l16)*DD + h2*32 + quad*8];
        }
    // drain Q-fragment loads so vmcnt below counts staging loads only
    VMCNTW(0); SCHEDB();

    const f32x4 zf = {0.f,0.f,0.f,0.f};
    f32x4 oaccA[2][4], oaccB[2][4];
    float lsumA[2][4], lsumB[2][4];
    #pragma unroll
    for (int m=0;m<2;m++){
        #pragma unroll
        for (int dt=0;dt<4;dt++){ oaccA[m][dt]=zf; oaccB[m][dt]=zf; }
        #pragma unroll
        for (int r=0;r<4;r++){ lsumA[m][r]=0.f; lsumB[m][r]=0.f; }
    }

    const int ktMax = 31 - 2*pair;     // tile B's diagonal (>= tile A's range)

    const int c0 = wave*64 + lane, c1 = 256 + wave*64 + lane;
    const int r0 = c0>>3, j0 = (c0&7) ^ (r0&7);
    const int r1 = c1>>3, j1 = (c1&7) ^ (r1&7);

#define STAGEKV(KT, BUF)                                                       \
  { const int s0 = (KT)*64;                                                    \
    gload_lds16(Kb  + (size_t)(s0+r0)*DD + j0*8, &Ks[BUF][wave*512]);          \
    gload_lds16(Kb  + (size_t)(s0+r1)*DD + j1*8, &Ks[BUF][(4+wave)*512]);      \
    gload_lds16(VTb + (size_t)r0*TT + s0 + j0*8, &Vs[BUF][wave*512]);          \
    gload_lds16(VTb + (size_t)r1*TT + s0 + j1*8, &Vs[BUF][(4+wave)*512]); }

    STAGEKV(0, 0);
    for (int kt=0; kt<=ktMax; kt++){
        const int b = kt&1;
        // prefetch next tile into the other buffer (freed by previous trailing BAR)
        if (kt < ktMax){ STAGEKV(kt+1, b^1); VMCNTW(4); }
        else           { VMCNTW(0); }
        BAR();
        attn_proc_tile(kt, qB0, quad, l16, Ks[b], Vs[b], Psw, qfB, oaccB, lsumB);
        attn_proc_tile(kt, qA0, quad, l16, Ks[b], Vs[b], Psw, qfA, oaccA, lsumA);
        BAR();
    }
#undef STAGEKV

    #pragma unroll
    for (int off=1; off<16; off<<=1)
        #pragma unroll
        for (int m=0;m<2;m++)
            #pragma unroll
            for (int r=0;r<4;r++){
                lsumA[m][r] += __shfl_xor(lsumA[m][r], off);
                lsumB[m][r] += __shfl_xor(lsumB[m][r], off);
            }

    const int bb = bh>>4, hh = bh&15;
    #pragma unroll
    for (int m=0;m<2;m++)
        #pragma unroll
        for (int dt=0;dt<4;dt++)
            #pragma unroll
            for (int r=0;r<4;r++){
                int t = qA0 + m*16 + quad*4 + r;
                O[(size_t)(bb*TT + t)*EE + hh*64 + dt*16 + l16] = f2bf(oaccA[m][dt][r] / lsumA[m][r]);
                t = qB0 + m*16 + quad*4 + r;
                O[(size_t)(bb*TT + t)*EE + hh*64 + dt*16 + l16] = f2bf(oaccB[m][dt][r] / lsumB[m][r]);
            }
}

extern "C" void kernel_launch(void* const* d_in, const int* in_sizes, int n_in,
                              void* d_out, int out_size, void* d_ws, size_t ws_size,
                              hipStream_t stream)
{
    (void)in_sizes; (void)n_in; (void)out_size; (void)ws_size;
    const int*   ids  = (const int*)d_in[0];
    const float* wte  = (const float*)d_in[1];
    const float* wpe  = (const float*)d_in[2];
    const float* wq   = (const float*)d_in[3];
    const float* wk   = (const float*)d_in[4];
    const float* wv   = (const float*)d_in[5];
    const float* bq   = (const float*)d_in[6];
    const float* bk   = (const float*)d_in[7];
    const float* bv   = (const float*)d_in[8];
    const float* wproj= (const float*)d_in[9];
    const float* bproj= (const float*)d_in[10];
    const float* ln1g = (const float*)d_in[11];
    const float* ln1b = (const float*)d_in[12];
    const float* ln2g = (const float*)d_in[13];
    const float* ln2b = (const float*)d_in[14];
    const float* wfc  = (const float*)d_in[15];
    const float* bfc  = (const float*)d_in[16];
    const float* wout = (const float*)d_in[17];
    const float* bout = (const float*)d_in[18];

    const size_t MTOK = (size_t)MM*EE;       // 8M elems
    char* p = (char*)d_ws;
    float* x    = (float*)p;  p += MTOK*sizeof(float);
    u16*  h     = (u16*)p;    p += MTOK*sizeof(u16);
    u16*  Qb    = (u16*)p;    p += MTOK*sizeof(u16);
    u16*  Kb    = (u16*)p;    p += MTOK*sizeof(u16);
    u16*  Vb    = (u16*)p;    p += MTOK*sizeof(u16);
    u16*  Ob    = (u16*)p;    p += MTOK*sizeof(u16);
    u16*  fcact = Qb;                        // overlay: Q/K/V/O dead by MLP
    u16*  VTv   = h;                         // overlay: h dead between QKV gemm and LN2
    u16*  WqkvT = (u16*)p;    p += (size_t)3072*1024*sizeof(u16);
    float* biasq= (float*)p;  p += 3072*sizeof(float);
    u16*  wprojT= (u16*)p;    p += (size_t)1024*1024*sizeof(u16);
    u16*  wfcT  = (u16*)p;    p += (size_t)4096*1024*sizeof(u16);
    u16*  woutT = (u16*)p;    p += (size_t)1024*4096*sizeof(u16);
    float* out  = (float*)d_out;

    repack_qkv_tiled<<<dim3(2,32,48),dim3(32,8),0,stream>>>(wq,wk,wv,WqkvT);
    copy_bias_qkv<<<12,256,0,stream>>>(bq,bk,bv,biasq);
    transpose_tile<<<dim3(32,32), dim3(32,8),0,stream>>>(wproj, wprojT, 1024, 1024);
    transpose_tile<<<dim3(128,32),dim3(32,8),0,stream>>>(wfc,   wfcT,   4096, 1024);
    transpose_tile<<<dim3(32,128),dim3(32,8),0,stream>>>(wout,  woutT,  1024, 4096);
    embed_ln1<<<MM,256,0,stream>>>(ids, wte, wpe, ln1g, ln1b, x, h);
    // QKV: 128x256 tiles -> grid 768 = 3 exact rounds of 256 CUs
    gemm_qkv<<<768,512,0,stream>>>(h, WqkvT, biasq, Qb, Kb, Vb);
    transpose_v<<<dim3(64,2,64),dim3(32,8),0,stream>>>(Vb, VTv);
    attn_kernel<<<512,256,0,stream>>>(Qb,Kb,VTv,Ob);
    // proj: 128x256 -> grid 256 = full GPU
    gemm_proj<<<256,512,0,stream>>>(Ob, wprojT, bproj, x, x);
    ln_fwd<<<MM,256,0,stream>>>(x, ln2g, ln2b, h);
    // FC: 256x256 4-phase -> grid 512 = 2 exact rounds (best measured config)
    gemm_fc<<<512,512,0,stream>>>(h, wfcT, bfc, fcact);
    // out: 128x256 -> grid 256 = full GPU
    gemm_out<<<256,512,0,stream>>>(fcact, woutT, bout, out, x);
}